// Round 4
// baseline (192.953 us; speedup 1.0000x reference)
//
#include <hip/hip_runtime.h>
#include <hip/hip_bf16.h>
#include <cstdint>
#include <cstddef>

// Problem constants (from reference setup_inputs)
#define HH   16
#define BB   4
#define NN   4096
#define DD   1024
#define MM   (BB * NN)      // 16384 rows
#define NC   256            // scan chunks
#define LC   16             // chunk length (NC*LC == NN)
#define EPSV 1e-6f

typedef short short8 __attribute__((ext_vector_type(8)));   // 8 x bf16 (4 VGPRs)
typedef float floatx4 __attribute__((ext_vector_type(4)));

__device__ __forceinline__ void async_copy16(const void* g, void* l) {
    __builtin_amdgcn_global_load_lds(
        (const __attribute__((address_space(1))) void*)g,
        (__attribute__((address_space(3))) void*)l, 16, 0, 0);
}

__device__ __forceinline__ uint2 pack_bf16x4(float a, float b, float c, float d) {
    union { __hip_bfloat16 h[4]; uint2 u; } cv;
    cv.h[0] = __float2bfloat16(a); cv.h[1] = __float2bfloat16(b);
    cv.h[2] = __float2bfloat16(c); cv.h[3] = __float2bfloat16(d);
    return cv.u;
}

// ---- prep: W'[i,j] = o_w[i,j]*nw[j] (bf16)  +  meta in last block ---------
__global__ void k_prep(const float* __restrict__ ow, const float* __restrict__ nw,
                       const float* __restrict__ q, const float* __restrict__ k,
                       const float* __restrict__ ld,
                       __hip_bfloat16* __restrict__ wp, float* __restrict__ meta) {
    int tid = threadIdx.x;
    if (blockIdx.x < 1024) {
        size_t i4 = (size_t)blockIdx.x * 256 + tid;          // over D*D/4
        int j = (int)((i4 * 4) & (DD - 1));
        float4 v = ((const float4*)ow)[i4];
        ((uint2*)wp)[i4] = pack_bf16x4(v.x * nw[j], v.y * nw[j + 1],
                                       v.z * nw[j + 2], v.w * nw[j + 3]);
        return;
    }
    // meta: 256 threads, thread t covers channels 4t..4t+3 (head = t>>4)
    float p = 0.f;
    #pragma unroll
    for (int i = 0; i < 4; ++i) p += q[tid * 4 + i] * k[tid * 4 + i];
    #pragma unroll
    for (int off = 1; off < 16; off <<= 1) p += __shfl_xor(p, off);
    if ((tid & 15) == 0) meta[16 + (tid >> 4)] = p;          // c_h = dot(qh,kh)
    if (tid < HH) meta[tid] = 1.f / (1.f + expf(-ld[tid]));  // lam_h
}

// ---- pass A: chunk-local scan end values (float4 per thread) --------------
__global__ void k_chunk_end(const float* __restrict__ x, const float* __restrict__ meta,
                            float* __restrict__ E) {
    int b = blockIdx.x >> 8, c = blockIdx.x & (NC - 1);
    int j4 = threadIdx.x;                // float4 channel group 0..255
    float lam = meta[(j4 * 4) >> 6];     // 4-ch group never crosses a head
    const float4* xp = (const float4*)(x + ((size_t)(b * NN + c * LC)) * DD) + j4;
    float4 e = {0.f, 0.f, 0.f, 0.f};
    #pragma unroll
    for (int t = 0; t < LC; ++t) {
        float4 v = xp[(size_t)t * (DD / 4)];
        e.x = fmaf(lam, e.x, v.x); e.y = fmaf(lam, e.y, v.y);
        e.z = fmaf(lam, e.z, v.z); e.w = fmaf(lam, e.w, v.w);
    }
    ((float4*)(E + (size_t)blockIdx.x * DD))[j4] = e;
}

// ---- pass B: carry prefix via LDS transpose, IN-PLACE (E -> carries) ------
// Block handles 32 chains (one b, 32 consecutive channels) over all 256 chunks.
__global__ void k_carry(const float* __restrict__ meta, float* __restrict__ E) {
    __shared__ float tile[NC][33];       // +1 pad
    int b = blockIdx.x >> 5, jg = blockIdx.x & 31;   // 4 b x 32 j-groups
    int tid = threadIdx.x;               // 256 threads
    int cc = tid >> 5, jj = tid & 31;
    #pragma unroll
    for (int it = 0; it < 32; ++it) {
        int c = it * 8 + cc;
        tile[c][jj] = E[(size_t)(b * NC + c) * DD + jg * 32 + jj];
    }
    __syncthreads();
    if (tid < 32) {
        int j = jg * 32 + tid;           // 32-ch group never crosses a head
        float lam = meta[j >> 6];
        float lamL = lam;                // lam^16 via 4 squarings
        lamL *= lamL; lamL *= lamL; lamL *= lamL; lamL *= lamL;
        float p = 0.f;
        for (int c = 0; c < NC; ++c) {
            float e = tile[c][tid];
            tile[c][tid] = p;            // carry INTO chunk c
            p = fmaf(lamL, p, e);
        }
    }
    __syncthreads();
    #pragma unroll
    for (int it = 0; it < 32; ++it) {
        int c = it * 8 + cc;
        E[(size_t)(b * NC + c) * DD + jg * 32 + jj] = tile[c][jj];
    }
}

// ---- pass C: full scan w/ carry, scale, bf16 store, row sum-sq ------------
// Row sums via per-wave LDS partials; one plain store per row (no atomics).
__global__ void k_scan(const float* __restrict__ x, const float* __restrict__ meta,
                       const float* __restrict__ P, __hip_bfloat16* __restrict__ obf,
                       float* __restrict__ sumsq) {
    __shared__ float wpart[LC][5];
    int b = blockIdx.x >> 8, c = blockIdx.x & (NC - 1);
    int j4 = threadIdx.x;                // 0..255
    int w = threadIdx.x >> 6;
    int h = (j4 * 4) >> 6;
    float lam = meta[h];
    float ch  = meta[16 + h];
    int row0 = b * NN + c * LC;
    const float4* xp = (const float4*)(x + (size_t)row0 * DD) + j4;
    float4 y = ((const float4*)(P + (size_t)blockIdx.x * DD))[j4];
    #pragma unroll
    for (int t = 0; t < LC; ++t) {
        float4 v = xp[(size_t)t * (DD / 4)];
        y.x = fmaf(lam, y.x, v.x); y.y = fmaf(lam, y.y, v.y);
        y.z = fmaf(lam, y.z, v.z); y.w = fmaf(lam, y.w, v.w);
        float ox = ch * y.x, oy = ch * y.y, oz = ch * y.z, ow = ch * y.w;
        ((uint2*)(obf + (size_t)(row0 + t) * DD))[j4] = pack_bf16x4(ox, oy, oz, ow);
        float s = ox * ox + oy * oy + oz * oz + ow * ow;
        #pragma unroll
        for (int off = 32; off > 0; off >>= 1) s += __shfl_xor(s, off);
        if ((threadIdx.x & 63) == 0) wpart[t][w] = s;
    }
    __syncthreads();
    if (threadIdx.x < LC) {
        int t = threadIdx.x;
        sumsq[row0 + t] = wpart[t][0] + wpart[t][1] + wpart[t][2] + wpart[t][3];
    }
}

// ---- GEMM: out[m,i] = rs[m] * sum_j A[m,j] * W'[i,j] ----------------------
// 128x128 tile, BK=64, DOUBLE-BUFFERED LDS (64 KB), 4 waves (2x2), 4x4
// mfma_f32_16x16x32_bf16, XOR bank swizzle, prefetch issued AFTER the
// barrier so it overlaps the compute phase (exposed latency ~300cy not 900).
__launch_bounds__(256)
__global__ void k_gemm(const __hip_bfloat16* __restrict__ A,
                       const __hip_bfloat16* __restrict__ W,
                       const float* __restrict__ sumsq, float* __restrict__ out) {
    __shared__ __attribute__((aligned(16))) short sA[2][128 * 64];
    __shared__ __attribute__((aligned(16))) short sB[2][128 * 64];
    const int tid = threadIdx.x;
    const int l = tid & 63, w = tid >> 6;
    const int wm = w >> 1, wn = w & 1;           // 2x2 wave grid, 64x64 each
    const int g = blockIdx.x;
    const int bm = g & 127, bn = g >> 7;
    const int m0 = bm * 128, n0 = bn * 128;
    const short* Ag = (const short*)A;
    const short* Wg = (const short*)W;

    floatx4 acc[4][4] = {};

    // staging geometry: slot s = i*256 + tid covers 16B; row = s>>3,
    // swizzled col-octet c8 = (s&7) ^ (row&7)  (bank-conflict-free reads)
    int srow[4], scol[4];
    #pragma unroll
    for (int i = 0; i < 4; ++i) {
        int s = i * 256 + tid;
        srow[i] = s >> 3;
        scol[i] = ((s & 7) ^ ((s >> 3) & 7)) * 8;
    }

    // prologue: stage k-tile 0 into buffer 0
    #pragma unroll
    for (int i = 0; i < 4; ++i) {
        async_copy16(Ag + (size_t)(m0 + srow[i]) * 1024 + scol[i],
                     (char*)sA[0] + i * 4096 + w * 1024);
        async_copy16(Wg + (size_t)(n0 + srow[i]) * 1024 + scol[i],
                     (char*)sB[0] + i * 4096 + w * 1024);
    }

    for (int kt = 0; kt < 16; ++kt) {
        const int cur = kt & 1;
        __syncthreads();                 // drains stage(kt); guards LDS reuse
        if (kt < 15) {                   // prefetch kt+1 AFTER the drain barrier
            const int nxt = cur ^ 1, k0 = (kt + 1) * 64;
            #pragma unroll
            for (int i = 0; i < 4; ++i) {
                async_copy16(Ag + (size_t)(m0 + srow[i]) * 1024 + k0 + scol[i],
                             (char*)sA[nxt] + i * 4096 + w * 1024);
                async_copy16(Wg + (size_t)(n0 + srow[i]) * 1024 + k0 + scol[i],
                             (char*)sB[nxt] + i * 4096 + w * 1024);
            }
        }
        #pragma unroll
        for (int ks = 0; ks < 2; ++ks) {
            short8 af[4], bf[4];
            #pragma unroll
            for (int mt = 0; mt < 4; ++mt) {
                int row = wm * 64 + mt * 16 + (l & 15);
                int c8  = (ks * 4 + (l >> 4)) ^ (row & 7);
                af[mt] = *(const short8*)(&sA[cur][0] + row * 64 + c8 * 8);
            }
            #pragma unroll
            for (int nt = 0; nt < 4; ++nt) {
                int row = wn * 64 + nt * 16 + (l & 15);
                int c8  = (ks * 4 + (l >> 4)) ^ (row & 7);
                bf[nt] = *(const short8*)(&sB[cur][0] + row * 64 + c8 * 8);
            }
            #pragma unroll
            for (int mt = 0; mt < 4; ++mt)
                #pragma unroll
                for (int nt = 0; nt < 4; ++nt)
                    acc[mt][nt] = __builtin_amdgcn_mfma_f32_16x16x32_bf16(af[mt], bf[nt], acc[mt][nt], 0, 0, 0);
        }
    }

    // epilogue: RMSNorm scale + store. D[m,n]: row = quad*4+reg, col = lane&15
    #pragma unroll
    for (int mt = 0; mt < 4; ++mt) {
        #pragma unroll
        for (int r = 0; r < 4; ++r) {
            int mrow = m0 + wm * 64 + mt * 16 + (l >> 4) * 4 + r;
            float rs = rsqrtf(sumsq[mrow] * (1.f / 1024.f) + EPSV);
            #pragma unroll
            for (int nt = 0; nt < 4; ++nt) {
                int col = n0 + wn * 64 + nt * 16 + (l & 15);
                out[(size_t)mrow * 1024 + col] = acc[mt][nt][r] * rs;
            }
        }
    }
}

extern "C" void kernel_launch(void* const* d_in, const int* in_sizes, int n_in,
                              void* d_out, int out_size, void* d_ws, size_t ws_size,
                              hipStream_t stream) {
    const float* x  = (const float*)d_in[0];
    const float* q  = (const float*)d_in[1];
    const float* k  = (const float*)d_in[2];
    const float* ld = (const float*)d_in[3];
    const float* nw = (const float*)d_in[4];
    const float* ow = (const float*)d_in[5];
    float* out = (float*)d_out;

    char* ws = (char*)d_ws;
    // layout: meta[32]f | sumsq[M]f | E (4 MB, reused in-place for carries) |
    //         W' bf16 (2 MB) | O bf16 (33.5 MB)   — total 39,911,680 B
    float* meta  = (float*)(ws + 0);
    float* sumsq = (float*)(ws + 256);
    float* E     = (float*)(ws + 65792);
    __hip_bfloat16* Wp  = (__hip_bfloat16*)(ws + 4260096);
    __hip_bfloat16* Obf = (__hip_bfloat16*)(ws + 6357248);

    k_prep<<<1025, 256, 0, stream>>>(ow, nw, q, k, ld, Wp, meta);
    k_chunk_end<<<BB * NC, 256, 0, stream>>>(x, meta, E);
    k_carry<<<BB * 32, 256, 0, stream>>>(meta, E);
    k_scan<<<BB * NC, 256, 0, stream>>>(x, meta, E, Obf, sumsq);
    k_gemm<<<(MM / 128) * (DD / 128), 256, 0, stream>>>(Obf, Wp, sumsq, out);
}